// Round 10
// baseline (156.829 us; speedup 1.0000x reference)
//
#include <hip/hip_runtime.h>
#include <float.h>

#define K_CODES 1024
#define DIM 64
#define T_LEN 8192
#define N_TOK 131072          // 16 * 8192 tokens
#define LO_SCALE 2048.0f

typedef _Float16 half8 __attribute__((ext_vector_type(8)));  // 4 VGPRs: MFMA A/B frag
typedef float    f32x4 __attribute__((ext_vector_type(4)));  // MFMA C/D frag

#define MFMA16(a, b, c) __builtin_amdgcn_mfma_f32_16x16x32_f16((a), (b), (c), 0, 0, 0)

// ---------------- prep: codebook -> tiled f16 hi/lo + 2048*e_sq ----------------
// Tile ct (16 codes) = 4 KB contiguous: hi[q=0..7][code=0..15][j=0..7], lo(x2048) at +1024.
// wesq stores 2048*||e||^2 (exact power-of-2 scale) for the scaled-score argmin.
__global__ void vq_prep(const float* __restrict__ cb,
                        _Float16* __restrict__ w,
                        float* __restrict__ wesq) {
    __shared__ float part[128];
    const int ct   = blockIdx.x;
    const int r    = threadIdx.x;
    const int halF = r >> 7;
    const int rr   = r & 127;
    const int q    = rr >> 4;
    const int code = rr & 15;

    const float* src = cb + (size_t)(ct * 16 + code) * DIM + q * 8;
    float4 v0 = *reinterpret_cast<const float4*>(src);
    float4 v1 = *reinterpret_cast<const float4*>(src + 4);
    float x[8] = {v0.x, v0.y, v0.z, v0.w, v1.x, v1.y, v1.z, v1.w};

    half8 o;
    float psum = 0.0f;
    #pragma unroll
    for (int j = 0; j < 8; ++j) {
        _Float16 h = (_Float16)x[j];
        o[j] = halF ? (_Float16)((x[j] - (float)h) * LO_SCALE) : h;  // (x-h) exact in fp32
        psum = fmaf(x[j], x[j], psum);
    }
    *reinterpret_cast<half8*>(w + (size_t)ct * 2048 + halF * 1024 + q * 128 + code * 8) = o;

    if (halF == 0) part[rr] = psum;
    __syncthreads();
    if (r < 16) {
        float s = 0.0f;
        #pragma unroll
        for (int q2 = 0; q2 < 8; ++q2) s += part[q2 * 16 + r];
        wesq[ct * 16 + r] = s * LO_SCALE;   // pre-scaled: score' = 2048 * score
    }
}

// ---------------- main: r8 base + PHASE-ROTATED tile order (non-decaying decorrelation) ----
// Ledger r0-r9: only r8 (setprio + s_sleep stagger) moved the 61us plateau (-2.5%). Corrected
// arithmetic: MFMA-pipe floor 25us (1536 x 19.4cyc/SIMD x 2 waves), true argmin VALU ~5us
// (VALUBusy ~= MfmaUtil every round => it double-counts MFMA issue), HBM ~8us (L3-resident).
// The ~27us residual = BOTH SIMD-mate waves stalling at the same point: they run IDENTICAL
// tile streams; s_sleep staggers them but decays at the first common stall. Fix: each
// (block,wave)-parity phase starts the codebook walk at tile ph*16 and wraps (&63) -- the
// two waves on a SIMD never touch the same tile in the same step, so their bursts/stalls
// structurally interleave and CANNOT re-converge. Rotation changes visit ORDER only; the
// explicit tie-break (sc==best && code<bidx) makes the argmin order-independent =>
// result identical to r0/reference (lowest index among minima) in every case.
__global__ __launch_bounds__(256, 2)
void vq_main(const float* __restrict__ in,
             const float* __restrict__ cb,
             const _Float16* __restrict__ w,
             const float* __restrict__ wesq,
             float* __restrict__ out) {
    __shared__ float esq_s[K_CODES];   // 4 KB (scaled x2048)
    __shared__ int   idx_s[256];

    const int tid  = threadIdx.x;
    const int wave = tid >> 6;
    const int lane = tid & 63;
    const int lo4  = lane & 15;   // code residue (C col) / token residue (A m)
    const int quad = lane >> 4;   // k-octet selector; token-row group in C

    for (int k = tid; k < K_CODES; k += 256) esq_s[k] = wesq[k];
    __syncthreads();   // only barrier before the epilogue

    // ---- decorrelation phase: rotation start + small time stagger (r8) ----
    const int ph = ((blockIdx.x & 1) << 1) | (wave & 1);
    {
        if (ph == 1)      __builtin_amdgcn_s_sleep(4);
        else if (ph == 2) __builtin_amdgcn_s_sleep(8);
        else if (ph == 3) __builtin_amdgcn_s_sleep(12);
    }
    const int base = ph * 16;   // starting tile, walk wraps mod 64

    const int strip = blockIdx.x * 256 + wave * 64;   // 64 tokens per wave
    const int b  = strip >> 13;
    const int t0 = strip & 8191;

    // B frags (layout HW-verified r6): tile base + lane*8, frags at +0/+512/+1024/+1536
    const _Float16* wb = w + (size_t)lane * 8;

    half8 Ah0, Ah1, Al0, Al1, Bh0, Bh1, Bl0, Bl1;
    float Ae, Be;
    auto loadB = [&](int ct, half8& h0, half8& h1, half8& l0, half8& l1, float& es) {
        const _Float16* p = wb + (size_t)ct * 2048;
        h0 = *reinterpret_cast<const half8*>(p);          // hi, k 0..31
        h1 = *reinterpret_cast<const half8*>(p + 512);    // hi, k 32..63
        l0 = *reinterpret_cast<const half8*>(p + 1024);   // lo(x2048), k 0..31
        l1 = *reinterpret_cast<const half8*>(p + 1536);   // lo(x2048), k 32..63
        es = esq_s[ct * 16 + lo4];
    };

    // hoisted (r8): first two B tiles in flight while the A fragments are built
    loadB(base, Ah0, Ah1, Al0, Al1, Ae);
    loadB(base + 1, Bh0, Bh1, Bl0, Bl1, Be);

    // ---- A fragments: -2x -> ah (f16), ah_s = ah*2048 (exact), al = (x-ah)*2048 ----
    const float* xin = in + (size_t)b * DIM * T_LEN + t0;
    half8 a_h[4][2], a_hs[4][2], a_l[4][2];
    #pragma unroll
    for (int mt = 0; mt < 4; ++mt) {
        #pragma unroll
        for (int s = 0; s < 2; ++s) {
            half8 hh, hs, ll;
            #pragma unroll
            for (int j = 0; j < 8; ++j) {
                const int d = s * 32 + quad * 8 + j;
                float xv = -2.0f * xin[(size_t)d * T_LEN + mt * 16 + lo4];
                _Float16 h = (_Float16)xv;
                hh[j] = h;
                hs[j] = (_Float16)((float)h * LO_SCALE);            // exact exponent shift
                ll[j] = (_Float16)((xv - (float)h) * LO_SCALE);
            }
            a_h[mt][s] = hh;
            a_hs[mt][s] = hs;
            a_l[mt][s] = ll;
        }
    }

    float best[16];
    int   bidx[16];
    #pragma unroll
    for (int i = 0; i < 16; ++i) { best[i] = FLT_MAX; bidx[i] = 0x7FFFFFFF; }

    // Interleaved issue: 4 independent accumulator chains, pass-outer / mt-inner (r2).
    // Per-chain MFMA order unchanged since r0 -> bit-identical scores. Argmin update is
    // order-independent (explicit lowest-index tie-break) -> rotation-safe.
    auto step = [&](const half8& h0, const half8& h1, const half8& l0,
                    const half8& l1, float es, int ct) {
        const int code = ct * 16 + lo4;
        f32x4 c0 = {es, es, es, es}, c1 = {es, es, es, es};
        f32x4 c2 = {es, es, es, es}, c3 = {es, es, es, es};
        __builtin_amdgcn_s_setprio(1);     // favor this wave during its MFMA burst (r8)
        c0 = MFMA16(a_hs[0][0], h0, c0);   // pass 1: 2048*ah*bh (k 0..31)
        c1 = MFMA16(a_hs[1][0], h0, c1);
        c2 = MFMA16(a_hs[2][0], h0, c2);
        c3 = MFMA16(a_hs[3][0], h0, c3);
        c0 = MFMA16(a_hs[0][1], h1, c0);   // pass 2: 2048*ah*bh (k 32..63)
        c1 = MFMA16(a_hs[1][1], h1, c1);
        c2 = MFMA16(a_hs[2][1], h1, c2);
        c3 = MFMA16(a_hs[3][1], h1, c3);
        c0 = MFMA16(a_h[0][0], l0, c0);    // pass 3: ah*(2048*bl)
        c1 = MFMA16(a_h[1][0], l0, c1);
        c2 = MFMA16(a_h[2][0], l0, c2);
        c3 = MFMA16(a_h[3][0], l0, c3);
        c0 = MFMA16(a_h[0][1], l1, c0);    // pass 4
        c1 = MFMA16(a_h[1][1], l1, c1);
        c2 = MFMA16(a_h[2][1], l1, c2);
        c3 = MFMA16(a_h[3][1], l1, c3);
        c0 = MFMA16(a_l[0][0], h0, c0);    // pass 5: (2048*al)*bh
        c1 = MFMA16(a_l[1][0], h0, c1);
        c2 = MFMA16(a_l[2][0], h0, c2);
        c3 = MFMA16(a_l[3][0], h0, c3);
        c0 = MFMA16(a_l[0][1], h1, c0);    // pass 6
        c1 = MFMA16(a_l[1][1], h1, c1);
        c2 = MFMA16(a_l[2][1], h1, c2);
        c3 = MFMA16(a_l[3][1], h1, c3);
        __builtin_amdgcn_s_setprio(0);
        f32x4 cc[4] = {c0, c1, c2, c3};
        #pragma unroll
        for (int mt = 0; mt < 4; ++mt) {
            #pragma unroll
            for (int r = 0; r < 4; ++r) {
                float sc = cc[mt][r];           // scaled score, no fmaf needed
                const int i = mt * 4 + r;
                bool take = (sc < best[i]) || (sc == best[i] && code < bidx[i]);
                best[i] = take ? sc : best[i];
                bidx[i] = take ? code : bidx[i];
            }
        }
    };

    // ---- rotated ping-pong: tile (base+t)&63; next tile's loads fly during this step ----
    for (int p = 0; p < 31; ++p) {
        step(Ah0, Ah1, Al0, Al1, Ae, (base + 2 * p) & 63);
        loadB((base + 2 * p + 2) & 63, Ah0, Ah1, Al0, Al1, Ae);
        step(Bh0, Bh1, Bl0, Bl1, Be, (base + 2 * p + 1) & 63);
        loadB((base + 2 * p + 3) & 63, Bh0, Bh1, Bl0, Bl1, Be);
    }
    step(Ah0, Ah1, Al0, Al1, Ae, (base + 62) & 63);
    step(Bh0, Bh1, Bl0, Bl1, Be, (base + 63) & 63);

    // ---- cross-lane merge over the 16 code-residue lanes ----
    #pragma unroll
    for (int i = 0; i < 16; ++i) {
        float s = best[i];
        int  ix = bidx[i];
        #pragma unroll
        for (int off = 1; off < 16; off <<= 1) {
            float s2 = __shfl_xor(s, off, 64);
            int  ix2 = __shfl_xor(ix, off, 64);
            bool take = (s2 < s) || (s2 == s && ix2 < ix);  // tie -> lower index
            s  = take ? s2 : s;
            ix = take ? ix2 : ix;
        }
        if (lo4 == 0) {
            // token_local = mt*16 + quad*4 + r,  mt = i>>2, r = i&3
            idx_s[wave * 64 + (i >> 2) * 16 + quad * 4 + (i & 3)] = ix;
        }
    }
    __syncthreads();

    // ---- epilogue: 1 thread per token, gather exact fp32 row + coalesced stores ----
    const int token = blockIdx.x * 256 + tid;
    const int tb = token >> 13;
    const int tt = token & 8191;
    const int my_idx = idx_s[tid];

    out[(size_t)N_TOK * DIM + token] = (float)my_idx;   // index output

    const float* crow = cb + (size_t)my_idx * DIM;
    float* outv = out + (size_t)tb * DIM * T_LEN + tt;
    #pragma unroll
    for (int d0 = 0; d0 < DIM; d0 += 4) {
        float4 v = *reinterpret_cast<const float4*>(crow + d0);  // L2-hot gather
        outv[(size_t)(d0 + 0) * T_LEN] = v.x;
        outv[(size_t)(d0 + 1) * T_LEN] = v.y;
        outv[(size_t)(d0 + 2) * T_LEN] = v.z;
        outv[(size_t)(d0 + 3) * T_LEN] = v.w;
    }
}

extern "C" void kernel_launch(void* const* d_in, const int* in_sizes, int n_in,
                              void* d_out, int out_size, void* d_ws, size_t ws_size,
                              hipStream_t stream) {
    const float* in = (const float*)d_in[0];   // (16, 64, 8192) fp32
    const float* cb = (const float*)d_in[1];   // (1024, 64) fp32
    float* out = (float*)d_out;

    _Float16* w   = (_Float16*)d_ws;                       // 64 tiles * 4 KB = 256 KB
    float*   wesq = (float*)((char*)d_ws + 64 * 4096);     // 4 KB

    vq_prep<<<dim3(64), dim3(256), 0, stream>>>(cb, w, wesq);
    vq_main<<<dim3(N_TOK / 256), dim3(256), 0, stream>>>(in, cb, w, wesq, out);
}

// Round 11
// 149.034 us; speedup vs baseline: 1.0523x; 1.0523x over previous
//
#include <hip/hip_runtime.h>
#include <float.h>

#define K_CODES 1024
#define DIM 64
#define T_LEN 8192
#define N_TOK 131072          // 16 * 8192 tokens
#define LO_SCALE 2048.0f

typedef _Float16 half8  __attribute__((ext_vector_type(8)));   // 4 VGPRs: MFMA A/B frag
typedef float    f32x16 __attribute__((ext_vector_type(16)));  // 32x32 MFMA C/D frag

#define MFMA32(a, b, c) __builtin_amdgcn_mfma_f32_32x32x16_f16((a), (b), (c), 0, 0, 0)

// ---------------- prep: codebook -> 32-code tiles for 32x32x16 MFMA ----------------
// Tile ct (32 codes) = 8 KB: hi frags [kf=0..3][o=0..1][code=0..31][j=0..7], lo(x2048)
// at +2048 f16. Lane l of the B frag reads tile_base + l*8 + kf*512 (16B contiguous):
// col=lane&31, k=(lane>>5)*8+j -- the same mapping rule as the HW-verified 16x16 tiles.
// wesq stores 2048*||e||^2 (exact power-of-2 scale) for the scaled-score argmin.
__global__ void vq_prep(const float* __restrict__ cb,
                        _Float16* __restrict__ w,
                        float* __restrict__ wesq) {
    __shared__ float part[256];
    const int ct = blockIdx.x;     // 32 tiles of 32 codes
    const int t  = threadIdx.x;    // 256 threads
    const int c  = t & 31;         // code within tile
    const int kq = t >> 5;         // k-octet 0..7 (dims d = kq*8+j)

    const float* src = cb + (size_t)(ct * 32 + c) * DIM + kq * 8;
    float4 v0 = *reinterpret_cast<const float4*>(src);
    float4 v1 = *reinterpret_cast<const float4*>(src + 4);
    float x[8] = {v0.x, v0.y, v0.z, v0.w, v1.x, v1.y, v1.z, v1.w};

    half8 oh, ol;
    float psum = 0.0f;
    #pragma unroll
    for (int j = 0; j < 8; ++j) {
        _Float16 h = (_Float16)x[j];
        oh[j] = h;
        ol[j] = (_Float16)((x[j] - (float)h) * LO_SCALE);   // (x-h) exact in fp32
        psum = fmaf(x[j], x[j], psum);
    }
    // off = kf*512 + o*256 + c*8,  kf = kq>>1, o = kq&1
    const size_t off = (size_t)ct * 4096 + (size_t)((kq >> 1) * 512 + (kq & 1) * 256 + c * 8);
    *reinterpret_cast<half8*>(w + off)        = oh;
    *reinterpret_cast<half8*>(w + off + 2048) = ol;

    part[t] = psum;
    __syncthreads();
    if (t < 32) {
        float s = 0.0f;
        #pragma unroll
        for (int kq2 = 0; kq2 < 8; ++kq2) s += part[kq2 * 32 + t];
        wesq[ct * 32 + t] = s * LO_SCALE;   // pre-scaled: score' = 2048 * score
    }
}

// ---------------- main: 32x32x16 MFMA, 32 tok/wave, 32 steps of 12 MFMAs ----------------
// r0-r10 ledger: the 16x16 structure carries a fixed per-step residual (~1100cyc/step-pair)
// that no schedule change (LDS, ILP, occupancy, prefetch depth, rotation) shrinks; only
// r8's setprio+stagger moved it (-2.5%). This round shrinks the STEP COUNT and issue count:
// 32x32x16 shape -> per wave 32 steps x 12 MFMAs x 32 codes (vs 64 x 24 x 16). Gains:
// (a) MFMA rate 2382 vs 2075 TF (floor 25->20.7us); (b) per-step residual amortized over
// half the steps; (c) per-wave argmin VALU halved. Fragment layouts: A/B row=lane&31,
// k=(lane>>5)*8+j (generalizes the HW-verified r6 16x16 rule); C/D col=lane&31,
// row=(reg&3)+8*(reg>>2)+4*(lane>>5) (doc-verified m74/m101). Same exact f16 product set;
// accumulation is one 12-chain (ulp-level reordering only -- argmin gaps >> ulp).
__global__ __launch_bounds__(256, 2)
void vq_main(const float* __restrict__ in,
             const float* __restrict__ cb,
             const _Float16* __restrict__ w,
             const float* __restrict__ wesq,
             float* __restrict__ out) {
    __shared__ float esq_s[K_CODES];   // 4 KB (scaled x2048)
    __shared__ int   idx_s[128];

    const int tid  = threadIdx.x;
    const int wave = tid >> 6;
    const int lane = tid & 63;
    const int col  = lane & 31;   // code col (B) / token row (A)
    const int o    = lane >> 5;   // k-octet half

    for (int k = tid; k < K_CODES; k += 256) esq_s[k] = wesq[k];
    __syncthreads();   // only barrier before the epilogue

    // ---- convoy breaker (r8): stagger co-resident waves ~256-768 cycles ----
    {
        const int ph = ((blockIdx.x & 1) << 1) | (wave & 1);
        if (ph == 1)      __builtin_amdgcn_s_sleep(4);
        else if (ph == 2) __builtin_amdgcn_s_sleep(8);
        else if (ph == 3) __builtin_amdgcn_s_sleep(12);
    }

    const int strip = blockIdx.x * 128 + wave * 32;   // 32 tokens per wave
    const int b  = strip >> 13;
    const int t0 = strip & 8191;

    // B frags: tile base + lane*8; frag kf at +kf*512, lo at +2048
    const _Float16* wb = w + (size_t)lane * 8;

    half8 Fh0[4], Fl0[4], Fh1[4], Fl1[4];
    float e0, e1;
    auto loadB = [&](int ct, half8 (&Fh)[4], half8 (&Fl)[4], float& es) {
        const _Float16* p = wb + (size_t)ct * 4096;
        #pragma unroll
        for (int kf = 0; kf < 4; ++kf) {
            Fh[kf] = *reinterpret_cast<const half8*>(p + kf * 512);
            Fl[kf] = *reinterpret_cast<const half8*>(p + kf * 512 + 2048);
        }
        es = esq_s[ct * 32 + col];
    };

    // hoisted (r8): first two B tiles in flight while the A fragments are built
    loadB(0, Fh0, Fl0, e0);
    loadB(1, Fh1, Fl1, e1);

    // ---- A fragments: -2x -> ah_s = ah*2048 (exact), ah, al = (x-ah)*2048 ----
    // A row = col (token), k = o*8 + j within each kf (dims d = kf*16 + o*8 + j)
    const float* xin = in + (size_t)b * DIM * T_LEN + t0;
    half8 a_hs[4], a_h[4], a_l[4];   // 48 VGPR
    #pragma unroll
    for (int kf = 0; kf < 4; ++kf) {
        half8 hh, hs, ll;
        #pragma unroll
        for (int j = 0; j < 8; ++j) {
            const int d = kf * 16 + o * 8 + j;
            float xv = -2.0f * xin[(size_t)d * T_LEN + col];
            _Float16 h = (_Float16)xv;
            hh[j] = h;
            hs[j] = (_Float16)((float)h * LO_SCALE);            // exact exponent shift
            ll[j] = (_Float16)((xv - (float)h) * LO_SCALE);
        }
        a_h[kf] = hh;
        a_hs[kf] = hs;
        a_l[kf] = ll;
    }

    float best[16];
    int   bidx[16];
    #pragma unroll
    for (int i = 0; i < 16; ++i) { best[i] = FLT_MAX; bidx[i] = 0; }

    // step: 12-MFMA chain (3 passes x 4 k-frags) + 16-candidate argmin
    auto step = [&](const half8 (&Fh)[4], const half8 (&Fl)[4], float es, int ct) {
        const int code = ct * 32 + col;
        f32x16 c;
        #pragma unroll
        for (int i = 0; i < 16; ++i) c[i] = es;   // 2048*||e||^2
        __builtin_amdgcn_s_setprio(1);            // favor this wave during its MFMA burst
        c = MFMA32(a_hs[0], Fh[0], c);   // pass 1: 2048*ah*bh
        c = MFMA32(a_hs[1], Fh[1], c);
        c = MFMA32(a_hs[2], Fh[2], c);
        c = MFMA32(a_hs[3], Fh[3], c);
        c = MFMA32(a_h[0], Fl[0], c);    // pass 2: ah*(2048*bl)
        c = MFMA32(a_h[1], Fl[1], c);
        c = MFMA32(a_h[2], Fl[2], c);
        c = MFMA32(a_h[3], Fl[3], c);
        c = MFMA32(a_l[0], Fh[0], c);    // pass 3: (2048*al)*bh
        c = MFMA32(a_l[1], Fh[1], c);
        c = MFMA32(a_l[2], Fh[2], c);
        c = MFMA32(a_l[3], Fh[3], c);
        __builtin_amdgcn_s_setprio(0);
        #pragma unroll
        for (int r = 0; r < 16; ++r) {
            float sc = c[r];                // scaled score, no fmaf needed
            bool lt = sc < best[r];         // strict <: first occurrence (lowest code) wins
            best[r] = lt ? sc : best[r];
            bidx[r] = lt ? code : bidx[r];
        }
    };

    // ---- ping-pong: tile ct+1's 8 loads in flight during tile ct's 12 MFMAs ----
    for (int p = 0; p < 15; ++p) {
        step(Fh0, Fl0, e0, 2 * p);
        loadB(2 * p + 2, Fh0, Fl0, e0);
        step(Fh1, Fl1, e1, 2 * p + 1);
        loadB(2 * p + 3, Fh1, Fl1, e1);
    }
    step(Fh0, Fl0, e0, 30);
    step(Fh1, Fl1, e1, 31);

    // ---- cross-lane merge: min over the 32 code-cols (stays within each o-half) ----
    #pragma unroll
    for (int i = 0; i < 16; ++i) {
        float s = best[i];
        int  ix = bidx[i];
        #pragma unroll
        for (int off = 1; off < 32; off <<= 1) {
            float s2 = __shfl_xor(s, off, 64);
            int  ix2 = __shfl_xor(ix, off, 64);
            bool take = (s2 < s) || (s2 == s && ix2 < ix);  // tie -> lower index
            s  = take ? s2 : s;
            ix = take ? ix2 : ix;
        }
        if (col == 0) {
            // token row = (i&3) + 8*(i>>2) + 4*o   (C/D mapping, reg=i)
            idx_s[wave * 32 + (i & 3) + 8 * (i >> 2) + 4 * o] = ix;
        }
    }
    __syncthreads();

    // ---- epilogue: 256 threads, 128 tokens: each thread does 32 of 64 dims ----
    const int tok_l = tid & 127;
    const int half_ = tid >> 7;
    const int token = blockIdx.x * 128 + tok_l;
    const int tb = token >> 13;
    const int tt = token & 8191;
    const int my_idx = idx_s[tok_l];

    if (half_ == 0)
        out[(size_t)N_TOK * DIM + token] = (float)my_idx;   // index output

    const float* crow = cb + (size_t)my_idx * DIM + half_ * 32;
    float* outv = out + (size_t)tb * DIM * T_LEN + (size_t)(half_ * 32) * T_LEN + tt;
    #pragma unroll
    for (int d0 = 0; d0 < 32; d0 += 4) {
        float4 v = *reinterpret_cast<const float4*>(crow + d0);  // L2-hot gather
        outv[(size_t)(d0 + 0) * T_LEN] = v.x;
        outv[(size_t)(d0 + 1) * T_LEN] = v.y;
        outv[(size_t)(d0 + 2) * T_LEN] = v.z;
        outv[(size_t)(d0 + 3) * T_LEN] = v.w;
    }
}

extern "C" void kernel_launch(void* const* d_in, const int* in_sizes, int n_in,
                              void* d_out, int out_size, void* d_ws, size_t ws_size,
                              hipStream_t stream) {
    const float* in = (const float*)d_in[0];   // (16, 64, 8192) fp32
    const float* cb = (const float*)d_in[1];   // (1024, 64) fp32
    float* out = (float*)d_out;

    _Float16* w   = (_Float16*)d_ws;                       // 32 tiles * 8 KB = 256 KB
    float*   wesq = (float*)((char*)d_ws + 64 * 4096);     // 4 KB

    vq_prep<<<dim3(32), dim3(256), 0, stream>>>(cb, w, wesq);
    vq_main<<<dim3(N_TOK / 128), dim3(256), 0, stream>>>(in, cb, w, wesq, out);
}

// Round 12
// 136.210 us; speedup vs baseline: 1.1514x; 1.0941x over previous
//
#include <hip/hip_runtime.h>
#include <float.h>

#define K_CODES 1024
#define DIM 64
#define T_LEN 8192
#define N_TOK 131072          // 16 * 8192 tokens
#define LO_SCALE 2048.0f

typedef _Float16 half8 __attribute__((ext_vector_type(8)));  // 4 VGPRs: MFMA A/B frag
typedef float    f32x4 __attribute__((ext_vector_type(4)));  // MFMA C/D frag

#define MFMA16(a, b, c) __builtin_amdgcn_mfma_f32_16x16x32_f16((a), (b), (c), 0, 0, 0)

// ---------------- prep: codebook -> tiled f16 hi/lo + 2048*e_sq (r8, unchanged) ----------------
__global__ void vq_prep(const float* __restrict__ cb,
                        _Float16* __restrict__ w,
                        float* __restrict__ wesq) {
    __shared__ float part[128];
    const int ct   = blockIdx.x;
    const int r    = threadIdx.x;
    const int halF = r >> 7;
    const int rr   = r & 127;
    const int q    = rr >> 4;
    const int code = rr & 15;

    const float* src = cb + (size_t)(ct * 16 + code) * DIM + q * 8;
    float4 v0 = *reinterpret_cast<const float4*>(src);
    float4 v1 = *reinterpret_cast<const float4*>(src + 4);
    float x[8] = {v0.x, v0.y, v0.z, v0.w, v1.x, v1.y, v1.z, v1.w};

    half8 o;
    float psum = 0.0f;
    #pragma unroll
    for (int j = 0; j < 8; ++j) {
        _Float16 h = (_Float16)x[j];
        o[j] = halF ? (_Float16)((x[j] - (float)h) * LO_SCALE) : h;  // (x-h) exact in fp32
        psum = fmaf(x[j], x[j], psum);
    }
    *reinterpret_cast<half8*>(w + (size_t)ct * 2048 + halF * 1024 + q * 128 + code * 8) = o;

    if (halF == 0) part[rr] = psum;
    __syncthreads();
    if (r < 16) {
        float s = 0.0f;
        #pragma unroll
        for (int q2 = 0; q2 < 8; ++q2) s += part[q2 * 16 + r];
        wesq[ct * 16 + r] = s * LO_SCALE;   // pre-scaled: score' = 2048 * score
    }
}

// ---------------- main: T3+T4 -- global_load_lds ring (4-deep) + counted vmcnt + raw barrier ----
// r0-r11 ledger: private-B variants all pin at ~60us / 36% MfmaUtil -- exactly the documented
// "m97-structure" ceiling. This round ports the documented fix: cooperative LDS staging via
// global_load_lds (1 inst/wave/tile, 4x less L1 traffic), 4-deep ring = 3 tiles in flight,
// s_waitcnt vmcnt(2) (never 0 in steady state), raw s_barrier (no compiler drain), stage
// issued AFTER the barrier (WAR-safe: all reads of the overwritten buffer completed before
// that barrier), sched_barrier(0) pins the order. SIMD-mates come from different blocks
// (1 wave/SIMD per block) so cross-wave phase diversity survives; setprio arbitrates.
// Ring mirrors the tile byte-for-byte -> same frag offsets, same MFMA set and order as r8
// -> bit-identical scores and argmins.
__global__ __launch_bounds__(256, 2)
void vq_main(const float* __restrict__ in,
             const float* __restrict__ cb,
             const _Float16* __restrict__ w,
             const float* __restrict__ wesq,
             float* __restrict__ out) {
    __shared__ __align__(16) _Float16 ring[4 * 2048];   // 16 KB: 4-tile ring
    __shared__ float esq_s[K_CODES];                    // 4 KB (scaled x2048)
    __shared__ int   idx_s[256];

    const int tid  = threadIdx.x;
    const int wave = tid >> 6;
    const int lane = tid & 63;
    const int lo4  = lane & 15;   // code residue (C col) / token residue (A m)
    const int quad = lane >> 4;   // k-octet selector; token-row group in C

    for (int k = tid; k < K_CODES; k += 256) esq_s[k] = wesq[k];
    __syncthreads();

    // block-level stagger (intra-block waves are now barrier-paced)
    if (blockIdx.x & 1) __builtin_amdgcn_s_sleep(8);

    // ---- cooperative stage: wave w copies bytes [w*1024, w*1024+1024) of tile t ----
    auto stage = [&](int t) {
        const char* gsrc = (const char*)w + ((size_t)t << 12) + (wave << 10) + (lane << 4);
        _Float16* ldst = &ring[((t & 3) << 11) + (wave << 9)];   // wave-uniform base
        __builtin_amdgcn_global_load_lds(
            (const __attribute__((address_space(1))) unsigned int*)gsrc,
            (__attribute__((address_space(3))) unsigned int*)ldst,
            16, 0, 0);   // HW scatters lane*16 B
    };
    stage(0); stage(1); stage(2);   // 3 tiles in flight

    const int strip = blockIdx.x * 256 + wave * 64;   // 64 tokens per wave
    const int b  = strip >> 13;
    const int t0 = strip & 8191;

    // ---- A fragments (r8): -2x -> ah (f16), ah_s = ah*2048 (exact), al = (x-ah)*2048 ----
    const float* xin = in + (size_t)b * DIM * T_LEN + t0;
    half8 a_h[4][2], a_hs[4][2], a_l[4][2];
    #pragma unroll
    for (int mt = 0; mt < 4; ++mt) {
        #pragma unroll
        for (int s = 0; s < 2; ++s) {
            half8 hh, hs, ll;
            #pragma unroll
            for (int j = 0; j < 8; ++j) {
                const int d = s * 32 + quad * 8 + j;
                float xv = -2.0f * xin[(size_t)d * T_LEN + mt * 16 + lo4];
                _Float16 h = (_Float16)xv;
                hh[j] = h;
                hs[j] = (_Float16)((float)h * LO_SCALE);            // exact exponent shift
                ll[j] = (_Float16)((xv - (float)h) * LO_SCALE);
            }
            a_h[mt][s] = hh;
            a_hs[mt][s] = hs;
            a_l[mt][s] = ll;
        }
    }

    float best[16];
    int   bidx[16];
    #pragma unroll
    for (int i = 0; i < 16; ++i) { best[i] = FLT_MAX; bidx[i] = 0; }

    const _Float16* rl = ring + (size_t)lane * 8;   // per-lane frag base in ring

    // step: ds_read frags from ring buf B + 24-MFMA 4-chain (r2 order) + 3-op argmin
    auto step = [&](int t, int B) {
        const _Float16* p = rl + B * 2048;
        half8 h0 = *reinterpret_cast<const half8*>(p);          // hi, k 0..31
        half8 h1 = *reinterpret_cast<const half8*>(p + 512);    // hi, k 32..63
        half8 l0 = *reinterpret_cast<const half8*>(p + 1024);   // lo(x2048), k 0..31
        half8 l1 = *reinterpret_cast<const half8*>(p + 1536);   // lo(x2048), k 32..63
        float es = esq_s[t * 16 + lo4];
        const int code = t * 16 + lo4;
        f32x4 c0 = {es, es, es, es}, c1 = {es, es, es, es};
        f32x4 c2 = {es, es, es, es}, c3 = {es, es, es, es};
        __builtin_amdgcn_s_setprio(1);
        c0 = MFMA16(a_hs[0][0], h0, c0);   // pass 1: 2048*ah*bh (k 0..31)
        c1 = MFMA16(a_hs[1][0], h0, c1);
        c2 = MFMA16(a_hs[2][0], h0, c2);
        c3 = MFMA16(a_hs[3][0], h0, c3);
        c0 = MFMA16(a_hs[0][1], h1, c0);   // pass 2: 2048*ah*bh (k 32..63)
        c1 = MFMA16(a_hs[1][1], h1, c1);
        c2 = MFMA16(a_hs[2][1], h1, c2);
        c3 = MFMA16(a_hs[3][1], h1, c3);
        c0 = MFMA16(a_h[0][0], l0, c0);    // pass 3: ah*(2048*bl)
        c1 = MFMA16(a_h[1][0], l0, c1);
        c2 = MFMA16(a_h[2][0], l0, c2);
        c3 = MFMA16(a_h[3][0], l0, c3);
        c0 = MFMA16(a_h[0][1], l1, c0);    // pass 4
        c1 = MFMA16(a_h[1][1], l1, c1);
        c2 = MFMA16(a_h[2][1], l1, c2);
        c3 = MFMA16(a_h[3][1], l1, c3);
        c0 = MFMA16(a_l[0][0], h0, c0);    // pass 5: (2048*al)*bh
        c1 = MFMA16(a_l[1][0], h0, c1);
        c2 = MFMA16(a_l[2][0], h0, c2);
        c3 = MFMA16(a_l[3][0], h0, c3);
        c0 = MFMA16(a_l[0][1], h1, c0);    // pass 6
        c1 = MFMA16(a_l[1][1], h1, c1);
        c2 = MFMA16(a_l[2][1], h1, c2);
        c3 = MFMA16(a_l[3][1], h1, c3);
        __builtin_amdgcn_s_setprio(0);
        f32x4 cc[4] = {c0, c1, c2, c3};
        #pragma unroll
        for (int mt = 0; mt < 4; ++mt) {
            #pragma unroll
            for (int r = 0; r < 4; ++r) {
                float sc = cc[mt][r];
                const int i = mt * 4 + r;
                bool lt = sc < best[i];         // strict <: first occurrence wins
                best[i] = lt ? sc : best[i];
                bidx[i] = lt ? code : bidx[i];
            }
        }
    };

    // PHASE(N): wait my tile landed (counted, never drains the pipeline), sync, pin order.
    // stage(t+3) AFTER the barrier: all reads of buf[(t+3)&3] (iter t-1) completed before it.
#define PHASE(N)                                          \
    asm volatile("s_waitcnt vmcnt(" #N ")" ::: "memory"); \
    __builtin_amdgcn_s_barrier();                         \
    __builtin_amdgcn_sched_barrier(0);

    for (int q = 0; q < 15; ++q) {
        const int t = q * 4;
        PHASE(2) stage(t + 3); step(t, 0);
        PHASE(2) stage(t + 4); step(t + 1, 1);
        PHASE(2) stage(t + 5); step(t + 2, 2);
        PHASE(2) stage(t + 6); step(t + 3, 3);
    }
    PHASE(2) stage(63); step(60, 0);
    PHASE(2)            step(61, 1);
    PHASE(1)            step(62, 2);
    PHASE(0)            step(63, 3);
#undef PHASE

    // ---- cross-lane merge over the 16 code-residue lanes (r8) ----
    #pragma unroll
    for (int i = 0; i < 16; ++i) {
        float s = best[i];
        int  ix = bidx[i];
        #pragma unroll
        for (int off = 1; off < 16; off <<= 1) {
            float s2 = __shfl_xor(s, off, 64);
            int  ix2 = __shfl_xor(ix, off, 64);
            bool take = (s2 < s) || (s2 == s && ix2 < ix);  // tie -> lower index
            s  = take ? s2 : s;
            ix = take ? ix2 : ix;
        }
        if (lo4 == 0) {
            // token_local = mt*16 + quad*4 + r,  mt = i>>2, r = i&3
            idx_s[wave * 64 + (i >> 2) * 16 + quad * 4 + (i & 3)] = ix;
        }
    }
    __syncthreads();

    // ---- epilogue: 1 thread per token, gather exact fp32 row + coalesced stores (r8) ----
    const int token = blockIdx.x * 256 + tid;
    const int tb = token >> 13;
    const int tt = token & 8191;
    const int my_idx = idx_s[tid];

    out[(size_t)N_TOK * DIM + token] = (float)my_idx;   // index output

    const float* crow = cb + (size_t)my_idx * DIM;
    float* outv = out + (size_t)tb * DIM * T_LEN + tt;
    #pragma unroll
    for (int d0 = 0; d0 < DIM; d0 += 4) {
        float4 v = *reinterpret_cast<const float4*>(crow + d0);  // L2-hot gather
        outv[(size_t)(d0 + 0) * T_LEN] = v.x;
        outv[(size_t)(d0 + 1) * T_LEN] = v.y;
        outv[(size_t)(d0 + 2) * T_LEN] = v.z;
        outv[(size_t)(d0 + 3) * T_LEN] = v.w;
    }
}

extern "C" void kernel_launch(void* const* d_in, const int* in_sizes, int n_in,
                              void* d_out, int out_size, void* d_ws, size_t ws_size,
                              hipStream_t stream) {
    const float* in = (const float*)d_in[0];   // (16, 64, 8192) fp32
    const float* cb = (const float*)d_in[1];   // (1024, 64) fp32
    float* out = (float*)d_out;

    _Float16* w   = (_Float16*)d_ws;                       // 64 tiles * 4 KB = 256 KB
    float*   wesq = (float*)((char*)d_ws + 64 * 4096);     // 4 KB

    vq_prep<<<dim3(64), dim3(256), 0, stream>>>(cb, w, wesq);
    vq_main<<<dim3(N_TOK / 256), dim3(256), 0, stream>>>(in, cb, w, wesq, out);
}

// Round 14
// 127.436 us; speedup vs baseline: 1.2306x; 1.0688x over previous
//
#include <hip/hip_runtime.h>
#include <float.h>

#define K_CODES 1024
#define DIM 64
#define T_LEN 8192
#define N_TOK 131072          // 16 * 8192 tokens
#define LO_SCALE 2048.0f

typedef _Float16 half8 __attribute__((ext_vector_type(8)));  // 4 VGPRs: MFMA A/B frag
typedef float    f32x4 __attribute__((ext_vector_type(4)));  // MFMA C/D frag

#define MFMA16(a, b, c) __builtin_amdgcn_mfma_f32_16x16x32_f16((a), (b), (c), 0, 0, 0)

// ---------------- prep: codebook -> tiled f16 hi/lo + 2048*e_sq (r8, unchanged) ----------------
__global__ void vq_prep(const float* __restrict__ cb,
                        _Float16* __restrict__ w,
                        float* __restrict__ wesq) {
    __shared__ float part[128];
    const int ct   = blockIdx.x;
    const int r    = threadIdx.x;
    const int halF = r >> 7;
    const int rr   = r & 127;
    const int q    = rr >> 4;
    const int code = rr & 15;

    const float* src = cb + (size_t)(ct * 16 + code) * DIM + q * 8;
    float4 v0 = *reinterpret_cast<const float4*>(src);
    float4 v1 = *reinterpret_cast<const float4*>(src + 4);
    float x[8] = {v0.x, v0.y, v0.z, v0.w, v1.x, v1.y, v1.z, v1.w};

    half8 o;
    float psum = 0.0f;
    #pragma unroll
    for (int j = 0; j < 8; ++j) {
        _Float16 h = (_Float16)x[j];
        o[j] = halF ? (_Float16)((x[j] - (float)h) * LO_SCALE) : h;  // (x-h) exact in fp32
        psum = fmaf(x[j], x[j], psum);
    }
    *reinterpret_cast<half8*>(w + (size_t)ct * 2048 + halF * 1024 + q * 128 + code * 8) = o;

    if (halF == 0) part[rr] = psum;
    __syncthreads();
    if (r < 16) {
        float s = 0.0f;
        #pragma unroll
        for (int q2 = 0; q2 < 8; ++q2) s += part[q2 * 16 + r];
        wesq[ct * 16 + r] = s * LO_SCALE;   // pre-scaled: score' = 2048 * score
    }
}

// ---------------- main: r8 structure + relaxed VGPR budget (launch_bounds 256,1) ----------------
// r13 (amdgpu_num_vgpr attr) died in infra before producing data; same experiment, standard
// spelling. Theory: all rounds allocated only 64-128 arch VGPRs vs ~190 live regs -> state in
// AGPRs, v_accvgpr round-trips tracking the MFMA stream (VALUBusy ~= MfmaUtil in all 13
// rounds, far above the ~6us algorithmic argmin VALU). min-waves=1 gives the allocator a
// 512-VGPR budget -> no reason to use AGPRs for VALU-touched state. r3 showed occupancy
// 2-vs-4 waves/SIMD is perf-neutral here, so the possible 1-wave/SIMD downside is bounded.
// Kernel body bit-identical to r8 -> identical numerics.
__global__ __launch_bounds__(256, 1)
void vq_main(const float* __restrict__ in,
             const float* __restrict__ cb,
             const _Float16* __restrict__ w,
             const float* __restrict__ wesq,
             float* __restrict__ out) {
    __shared__ float esq_s[K_CODES];   // 4 KB (scaled x2048)
    __shared__ int   idx_s[256];

    const int tid  = threadIdx.x;
    const int wave = tid >> 6;
    const int lane = tid & 63;
    const int lo4  = lane & 15;   // code residue (C col) / token residue (A m)
    const int quad = lane >> 4;   // k-octet selector; token-row group in C

    for (int k = tid; k < K_CODES; k += 256) esq_s[k] = wesq[k];
    __syncthreads();   // only barrier before the epilogue

    // ---- convoy breaker (r8): stagger co-resident waves ~256-768 cycles ----
    {
        const int ph = ((blockIdx.x & 1) << 1) | (wave & 1);
        if (ph == 1)      __builtin_amdgcn_s_sleep(4);
        else if (ph == 2) __builtin_amdgcn_s_sleep(8);
        else if (ph == 3) __builtin_amdgcn_s_sleep(12);
    }

    const int strip = blockIdx.x * 256 + wave * 64;   // 64 tokens per wave
    const int b  = strip >> 13;
    const int t0 = strip & 8191;

    // B frags (layout HW-verified r6): tile base + lane*8, frags at +0/+512/+1024/+1536
    const _Float16* wb = w + (size_t)lane * 8;

    half8 Ah0, Ah1, Al0, Al1, Bh0, Bh1, Bl0, Bl1;
    float Ae, Be;
    auto loadB = [&](int ct, half8& h0, half8& h1, half8& l0, half8& l1, float& es) {
        const _Float16* p = wb + (size_t)ct * 2048;
        h0 = *reinterpret_cast<const half8*>(p);          // hi, k 0..31
        h1 = *reinterpret_cast<const half8*>(p + 512);    // hi, k 32..63
        l0 = *reinterpret_cast<const half8*>(p + 1024);   // lo(x2048), k 0..31
        l1 = *reinterpret_cast<const half8*>(p + 1536);   // lo(x2048), k 32..63
        es = esq_s[ct * 16 + lo4];
    };

    // hoisted (r8): first two B tiles in flight while the A fragments are built
    loadB(0, Ah0, Ah1, Al0, Al1, Ae);
    loadB(1, Bh0, Bh1, Bl0, Bl1, Be);

    // ---- A fragments: -2x -> ah (f16), ah_s = ah*2048 (exact), al = (x-ah)*2048 ----
    const float* xin = in + (size_t)b * DIM * T_LEN + t0;
    half8 a_h[4][2], a_hs[4][2], a_l[4][2];
    #pragma unroll
    for (int mt = 0; mt < 4; ++mt) {
        #pragma unroll
        for (int s = 0; s < 2; ++s) {
            half8 hh, hs, ll;
            #pragma unroll
            for (int j = 0; j < 8; ++j) {
                const int d = s * 32 + quad * 8 + j;
                float xv = -2.0f * xin[(size_t)d * T_LEN + mt * 16 + lo4];
                _Float16 h = (_Float16)xv;
                hh[j] = h;
                hs[j] = (_Float16)((float)h * LO_SCALE);            // exact exponent shift
                ll[j] = (_Float16)((xv - (float)h) * LO_SCALE);
            }
            a_h[mt][s] = hh;
            a_hs[mt][s] = hs;
            a_l[mt][s] = ll;
        }
    }

    float best[16];
    int   bidx[16];
    #pragma unroll
    for (int i = 0; i < 16; ++i) { best[i] = FLT_MAX; bidx[i] = 0; }

    // Interleaved issue: 4 independent accumulator chains, pass-outer / mt-inner (r2).
    // Same per-chain MFMA order as r0/r2 -> bit-identical scores.
    auto step = [&](const half8& h0, const half8& h1, const half8& l0,
                    const half8& l1, float es, int ct) {
        const int code = ct * 16 + lo4;
        f32x4 c0 = {es, es, es, es}, c1 = {es, es, es, es};
        f32x4 c2 = {es, es, es, es}, c3 = {es, es, es, es};
        __builtin_amdgcn_s_setprio(1);     // favor this wave during its MFMA burst (r8)
        c0 = MFMA16(a_hs[0][0], h0, c0);   // pass 1: 2048*ah*bh (k 0..31)
        c1 = MFMA16(a_hs[1][0], h0, c1);
        c2 = MFMA16(a_hs[2][0], h0, c2);
        c3 = MFMA16(a_hs[3][0], h0, c3);
        c0 = MFMA16(a_hs[0][1], h1, c0);   // pass 2: 2048*ah*bh (k 32..63)
        c1 = MFMA16(a_hs[1][1], h1, c1);
        c2 = MFMA16(a_hs[2][1], h1, c2);
        c3 = MFMA16(a_hs[3][1], h1, c3);
        c0 = MFMA16(a_h[0][0], l0, c0);    // pass 3: ah*(2048*bl)
        c1 = MFMA16(a_h[1][0], l0, c1);
        c2 = MFMA16(a_h[2][0], l0, c2);
        c3 = MFMA16(a_h[3][0], l0, c3);
        c0 = MFMA16(a_h[0][1], l1, c0);    // pass 4
        c1 = MFMA16(a_h[1][1], l1, c1);
        c2 = MFMA16(a_h[2][1], l1, c2);
        c3 = MFMA16(a_h[3][1], l1, c3);
        c0 = MFMA16(a_l[0][0], h0, c0);    // pass 5: (2048*al)*bh
        c1 = MFMA16(a_l[1][0], h0, c1);
        c2 = MFMA16(a_l[2][0], h0, c2);
        c3 = MFMA16(a_l[3][0], h0, c3);
        c0 = MFMA16(a_l[0][1], h1, c0);    // pass 6
        c1 = MFMA16(a_l[1][1], h1, c1);
        c2 = MFMA16(a_l[2][1], h1, c2);
        c3 = MFMA16(a_l[3][1], h1, c3);
        __builtin_amdgcn_s_setprio(0);     // back to normal for the argmin VALU burst
        f32x4 cc[4] = {c0, c1, c2, c3};
        #pragma unroll
        for (int mt = 0; mt < 4; ++mt) {
            #pragma unroll
            for (int r = 0; r < 4; ++r) {
                float sc = cc[mt][r];           // scaled score, no fmaf needed
                const int i = mt * 4 + r;
                bool lt = sc < best[i];         // strict <: first occurrence wins
                best[i] = lt ? sc : best[i];
                bidx[i] = lt ? code : bidx[i];
            }
        }
    };

    // ping-pong: tile ct+1's 4 global loads in flight during tile ct's 24 MFMAs
    for (int p = 0; p < 31; ++p) {
        step(Ah0, Ah1, Al0, Al1, Ae, 2 * p);
        loadB(2 * p + 2, Ah0, Ah1, Al0, Al1, Ae);
        step(Bh0, Bh1, Bl0, Bl1, Be, 2 * p + 1);
        loadB(2 * p + 3, Bh0, Bh1, Bl0, Bl1, Be);
    }
    step(Ah0, Ah1, Al0, Al1, Ae, 62);
    step(Bh0, Bh1, Bl0, Bl1, Be, 63);

    // ---- cross-lane merge over the 16 code-residue lanes ----
    #pragma unroll
    for (int i = 0; i < 16; ++i) {
        float s = best[i];
        int  ix = bidx[i];
        #pragma unroll
        for (int off = 1; off < 16; off <<= 1) {
            float s2 = __shfl_xor(s, off, 64);
            int  ix2 = __shfl_xor(ix, off, 64);
            bool take = (s2 < s) || (s2 == s && ix2 < ix);  // tie -> lower index
            s  = take ? s2 : s;
            ix = take ? ix2 : ix;
        }
        if (lo4 == 0) {
            // token_local = mt*16 + quad*4 + r,  mt = i>>2, r = i&3
            idx_s[wave * 64 + (i >> 2) * 16 + quad * 4 + (i & 3)] = ix;
        }
    }
    __syncthreads();

    // ---- epilogue: 1 thread per token, gather exact fp32 row + coalesced stores ----
    const int token = blockIdx.x * 256 + tid;
    const int tb = token >> 13;
    const int tt = token & 8191;
    const int my_idx = idx_s[tid];

    out[(size_t)N_TOK * DIM + token] = (float)my_idx;   // index output

    const float* crow = cb + (size_t)my_idx * DIM;
    float* outv = out + (size_t)tb * DIM * T_LEN + tt;
    #pragma unroll
    for (int d0 = 0; d0 < DIM; d0 += 4) {
        float4 v = *reinterpret_cast<const float4*>(crow + d0);  // L2-hot gather
        outv[(size_t)(d0 + 0) * T_LEN] = v.x;
        outv[(size_t)(d0 + 1) * T_LEN] = v.y;
        outv[(size_t)(d0 + 2) * T_LEN] = v.z;
        outv[(size_t)(d0 + 3) * T_LEN] = v.w;
    }
}

extern "C" void kernel_launch(void* const* d_in, const int* in_sizes, int n_in,
                              void* d_out, int out_size, void* d_ws, size_t ws_size,
                              hipStream_t stream) {
    const float* in = (const float*)d_in[0];   // (16, 64, 8192) fp32
    const float* cb = (const float*)d_in[1];   // (1024, 64) fp32
    float* out = (float*)d_out;

    _Float16* w   = (_Float16*)d_ws;                       // 64 tiles * 4 KB = 256 KB
    float*   wesq = (float*)((char*)d_ws + 64 * 4096);     // 4 KB

    vq_prep<<<dim3(64), dim3(256), 0, stream>>>(cb, w, wesq);
    vq_main<<<dim3(N_TOK / 256), dim3(256), 0, stream>>>(in, cb, w, wesq, out);
}